// Round 9
// baseline (163.530 us; speedup 1.0000x reference)
//
#include <hip/hip_runtime.h>

// ---------------- compile-time constants (constexpr Newton sqrt) ------------
constexpr double csqrt(double x) {
    double r = x > 1.0 ? x : 1.0;
    for (int i = 0; i < 60; ++i) r = 0.5 * (r + x / r);
    return r;
}

constexpr double PI_D    = 3.14159265358979323846264338327950288;
constexpr double SQ2R    = csqrt(0.5);            // sqrt(1/2)
constexpr double SQ2PIR  = csqrt(0.5 / PI_D);     // sqrt(1/(2pi))
constexpr double C00_D   = SQ2PIR * SQ2R;         // Y00
constexpr double C1Y_D   = -csqrt(1.5) * SQ2PIR;  // p1[1]*sqrt(1/(2pi))

struct SphConsts {
    double ca[7][7];   // a(l,m) = sqrt((4l^2-1)/(l^2-m^2)),   l>=2, m<=l-2
    double cb[7][7];   // b(l,m) = -sqrt(((l-1)^2-m^2)/(4(l-1)^2-1))
    double p1[7];      // -sqrt(1 + 1/(2l))
    double p2[7];      // sqrt(2l+3)
};

constexpr SphConsts makeConsts() {
    SphConsts c{};
    for (int l = 1; l < 7; ++l) {
        for (int m = 0; m < l; ++m) {
            c.ca[l][m] = csqrt((4.0 * l * l - 1.0) / (double)(l * l - m * m));
            double num = (double)((l - 1) * (l - 1) - m * m);
            double den = 4.0 * (l - 1) * (l - 1) - 1.0;
            c.cb[l][m] = -csqrt(num / den < 0.0 ? 0.0 : num / den);
        }
        c.p1[l] = -csqrt(1.0 + 0.5 / (double)l);
    }
    for (int l = 0; l < 7; ++l) c.p2[l] = csqrt(2.0 * l + 3.0);
    return c;
}

constexpr SphConsts CC = makeConsts();

// ---------------- vector types + helpers ------------------------------------
typedef float f8 __attribute__((ext_vector_type(8)));

__device__ __forceinline__ void stv(float* p, float v) {
    __builtin_nontemporal_store(v, p);
}
__device__ __forceinline__ void stv(float* p, f8 v) {
    // 32 B per thread per row -> 2 KB contiguous per wave-store (2x dwordx4 nt)
    __builtin_nontemporal_store(v, reinterpret_cast<f8*>(p));
}

template <typename T> __device__ __forceinline__ T bcast(float v);
template <> __device__ __forceinline__ float bcast<float>(float v) { return v; }
template <> __device__ __forceinline__ f8    bcast<f8>(float v)    { f8 t = {v, v, v, v, v, v, v, v}; return t; }

// ---------------- per-point computation, column-major (m-major) -------------
// o points at out[point_idx]; row k lives at o + k*N.
// Column recurrence: sph[l,m] = a(l,m)*(z*sph[l-1,m] + b(l,m)*d2*sph[l-2,m])
// Diagonal chain:    dp_m = p1[m]*(x*dp_{m-1} - y*dn_{m-1}), dn analogous.
// First off-diag:    sph[m+1, m] = p2[m]*z*diag
// Row ids: yr[l,m] = l*l+l+m, yrr[l,m] = l*l+l-m.
template <typename T>
__device__ __forceinline__ void sph_point(T x, T y, T z, float* __restrict__ o, size_t N) {
    const T d2 = x * x + y * y + z * z;

    // ---- m = 0 column (rows l*l+l, l=0..6) ----
    T pa = bcast<T>((float)C00_D);          // l = 0
    stv(o + 0 * N, pa);
    T pb = (float)CC.p2[0] * (z * pa);      // l = 1
    stv(o + 2 * N, pb);
#pragma unroll
    for (int l = 2; l <= 6; ++l) {
        const float a = (float)CC.ca[l][0];
        const float b = (float)CC.cb[l][0];
        T pc = a * (z * pb + b * (d2 * pa));
        stv(o + (size_t)(l * l + l) * N, pc);
        pa = pb; pb = pc;
    }

    // ---- diagonal seeds at l = 1 ----
    T dp = (float)C1Y_D * x;                // sph[3] = yr[1,1]
    T dn = (float)C1Y_D * y;                // sph[1] = yrr[1,1]
    stv(o + 3 * N, dp);
    stv(o + 1 * N, dn);

    // ---- columns m = 1..6 ----
#pragma unroll
    for (int m = 1; m <= 6; ++m) {
        if (m >= 2) {
            // advance the diagonal to (m,m)
            const float p1v = (float)CC.p1[m];
            T ndp = p1v * (x * dp - y * dn);
            T ndn = p1v * (x * dn + y * dp);
            dp = ndp; dn = ndn;
            stv(o + (size_t)(m * m + 2 * m) * N, dp);   // yr[m,m]
            stv(o + (size_t)(m * m) * N, dn);           // yrr[m,m]
        }
        if (m <= 5) {
            // first off-diagonal: l = m+1
            const float p2v = (float)CC.p2[m];
            T qp = p2v * (z * dp);
            T qn = p2v * (z * dn);
            {
                const int l = m + 1;
                stv(o + (size_t)(l * l + l + m) * N, qp);
                stv(o + (size_t)(l * l + l - m) * N, qn);
            }
            // column walk l = m+2 .. 6
            T ap = dp, bp = qp, an = dn, bn = qn;
#pragma unroll
            for (int l = m + 2; l <= 6; ++l) {
                const float a = (float)CC.ca[l][m];
                const float b = (float)CC.cb[l][m];
                T cp = a * (z * bp + b * (d2 * ap));
                T cn = a * (z * bn + b * (d2 * an));
                stv(o + (size_t)(l * l + l + m) * N, cp);
                stv(o + (size_t)(l * l + l - m) * N, cn);
                ap = bp; bp = cp;
                an = bn; bn = cn;
            }
        }
    }
}

// ---------------- kernels (grid-stride) -------------------------------------
template <typename T, int W>
__global__ void sph_kernel(const float* __restrict__ cart,
                           float* __restrict__ out, int N) {
    const int nW = N / W;
    const size_t sN = (size_t)N;
    const int stride = gridDim.x * blockDim.x;
    for (int i = blockIdx.x * blockDim.x + threadIdx.x; i < nW; i += stride) {
        const float* p = cart + (size_t)W * i;
        T X = *reinterpret_cast<const T*>(p);
        T Y = *reinterpret_cast<const T*>(p + sN);
        T Z = *reinterpret_cast<const T*>(p + 2 * sN);
        sph_point<T>(X, Y, Z, out + (size_t)W * i, sN);
    }
}

// ---------------- launch ----------------------------------------------------
extern "C" void kernel_launch(void* const* d_in, const int* in_sizes, int n_in,
                              void* d_out, int out_size, void* d_ws, size_t ws_size,
                              hipStream_t stream) {
    const float* cart = (const float*)d_in[0];
    float* out = (float*)d_out;
    const int N = in_sizes[0] / 3;

    const int threads = 256;
    if ((N & 7) == 0) {
        const int n8 = N >> 3;
        int blocks = (n8 + threads - 1) / threads;
        if (blocks > 2048) blocks = 2048;
        sph_kernel<f8, 8><<<blocks, threads, 0, stream>>>(cart, out, N);
    } else {
        const int blocks = (N + threads - 1) / threads;
        sph_kernel<float, 1><<<blocks, threads, 0, stream>>>(cart, out, N);
    }
}

// Round 10
// 75.480 us; speedup vs baseline: 2.1665x; 2.1665x over previous
//
#include <hip/hip_runtime.h>

// ---------------- compile-time constants (constexpr Newton sqrt) ------------
constexpr double csqrt(double x) {
    double r = x > 1.0 ? x : 1.0;
    for (int i = 0; i < 60; ++i) r = 0.5 * (r + x / r);
    return r;
}

constexpr double PI_D    = 3.14159265358979323846264338327950288;
constexpr double SQ2R    = csqrt(0.5);            // sqrt(1/2)
constexpr double SQ2PIR  = csqrt(0.5 / PI_D);     // sqrt(1/(2pi))
constexpr double C00_D   = SQ2PIR * SQ2R;         // Y00
constexpr double C1Y_D   = -csqrt(1.5) * SQ2PIR;  // p1[1]*sqrt(1/(2pi))

struct SphConsts {
    double ca[7][7];   // a(l,m) = sqrt((4l^2-1)/(l^2-m^2)),   l>=2, m<=l-2
    double cb[7][7];   // b(l,m) = -sqrt(((l-1)^2-m^2)/(4(l-1)^2-1))
    double p1[7];      // -sqrt(1 + 1/(2l))
    double p2[7];      // sqrt(2l+3)
};

constexpr SphConsts makeConsts() {
    SphConsts c{};
    for (int l = 1; l < 7; ++l) {
        for (int m = 0; m < l; ++m) {
            c.ca[l][m] = csqrt((4.0 * l * l - 1.0) / (double)(l * l - m * m));
            double num = (double)((l - 1) * (l - 1) - m * m);
            double den = 4.0 * (l - 1) * (l - 1) - 1.0;
            c.cb[l][m] = -csqrt(num / den < 0.0 ? 0.0 : num / den);
        }
        c.p1[l] = -csqrt(1.0 + 0.5 / (double)l);
    }
    for (int l = 0; l < 7; ++l) c.p2[l] = csqrt(2.0 * l + 3.0);
    return c;
}

constexpr SphConsts CC = makeConsts();

// ---------------- vector types + helpers ------------------------------------
typedef float f4 __attribute__((ext_vector_type(4)));

__device__ __forceinline__ void stv(float* p, float v) {
    __builtin_nontemporal_store(v, p);
}
__device__ __forceinline__ void stv(float* p, f4 v) {
    __builtin_nontemporal_store(v, reinterpret_cast<f4*>(p));
}

template <typename T> __device__ __forceinline__ T bcast(float v);
template <> __device__ __forceinline__ float bcast<float>(float v) { return v; }
template <> __device__ __forceinline__ f4    bcast<f4>(float v)    { f4 t = {v, v, v, v}; return t; }

// ---------------- per-point computation, column-major (m-major) -------------
// o points at out[point_idx]; row k lives at o + k*N.
// Column recurrence: sph[l,m] = a(l,m)*(z*sph[l-1,m] + b(l,m)*d2*sph[l-2,m])
// Diagonal chain:    dp_m = p1[m]*(x*dp_{m-1} - y*dn_{m-1}),
//                    dn_m = p1[m]*(x*dn_{m-1} + y*dp_{m-1})   (seeded at m=1)
// First off-diag:    sph[m+1, m] = p2[m]*z*diag
// Row ids: yr[l,m] = l*l+l+m, yrr[l,m] = l*l+l-m.
template <typename T>
__device__ __forceinline__ void sph_point(T x, T y, T z, float* __restrict__ o, size_t N) {
    const T d2 = x * x + y * y + z * z;

    // ---- m = 0 column (rows l*l+l, l=0..6) ----
    T pa = bcast<T>((float)C00_D);          // l = 0
    stv(o + 0 * N, pa);
    T pb = (float)CC.p2[0] * (z * pa);      // l = 1
    stv(o + 2 * N, pb);
#pragma unroll
    for (int l = 2; l <= 6; ++l) {
        const float a = (float)CC.ca[l][0];
        const float b = (float)CC.cb[l][0];
        T pc = a * (z * pb + b * (d2 * pa));
        stv(o + (size_t)(l * l + l) * N, pc);
        pa = pb; pb = pc;
    }

    // ---- diagonal seeds at l = 1 ----
    T dp = (float)C1Y_D * x;                // sph[3] = yr[1,1]
    T dn = (float)C1Y_D * y;                // sph[1] = yrr[1,1]
    stv(o + 3 * N, dp);
    stv(o + 1 * N, dn);

    // ---- columns m = 1..6 ----
#pragma unroll
    for (int m = 1; m <= 6; ++m) {
        if (m >= 2) {
            // advance the diagonal to (m,m)
            const float p1v = (float)CC.p1[m];
            T ndp = p1v * (x * dp - y * dn);
            T ndn = p1v * (x * dn + y * dp);
            dp = ndp; dn = ndn;
            stv(o + (size_t)(m * m + 2 * m) * N, dp);   // yr[m,m]
            stv(o + (size_t)(m * m) * N, dn);           // yrr[m,m]
        }
        if (m <= 5) {
            // first off-diagonal: l = m+1
            const float p2v = (float)CC.p2[m];
            T qp = p2v * (z * dp);
            T qn = p2v * (z * dn);
            {
                const int l = m + 1;
                stv(o + (size_t)(l * l + l + m) * N, qp);
                stv(o + (size_t)(l * l + l - m) * N, qn);
            }
            // column walk l = m+2 .. 6
            T ap = dp, bp = qp, an = dn, bn = qn;
#pragma unroll
            for (int l = m + 2; l <= 6; ++l) {
                const float a = (float)CC.ca[l][m];
                const float b = (float)CC.cb[l][m];
                T cp = a * (z * bp + b * (d2 * ap));
                T cn = a * (z * bn + b * (d2 * an));
                stv(o + (size_t)(l * l + l + m) * N, cp);
                stv(o + (size_t)(l * l + l - m) * N, cn);
                ap = bp; bp = cp;
                an = bn; bn = cn;
            }
        }
    }
}

// ---------------- kernels ---------------------------------------------------
template <typename T, int W>
__global__ void sph_kernel(const float* __restrict__ cart,
                           float* __restrict__ out, int N) {
    const int i = blockIdx.x * blockDim.x + threadIdx.x;   // group of W points
    const int nW = N / W;
    if (i >= nW) return;
    const size_t sN = (size_t)N;
    const float* p = cart + (size_t)W * i;
    T X = *reinterpret_cast<const T*>(p);
    T Y = *reinterpret_cast<const T*>(p + sN);
    T Z = *reinterpret_cast<const T*>(p + 2 * sN);
    sph_point<T>(X, Y, Z, out + (size_t)W * i, sN);
}

// ---------------- launch ----------------------------------------------------
extern "C" void kernel_launch(void* const* d_in, const int* in_sizes, int n_in,
                              void* d_out, int out_size, void* d_ws, size_t ws_size,
                              hipStream_t stream) {
    const float* cart = (const float*)d_in[0];
    float* out = (float*)d_out;
    const int N = in_sizes[0] / 3;

    const int threads = 256;
    if ((N & 3) == 0) {
        const int n4 = N >> 2;
        const int blocks = (n4 + threads - 1) / threads;
        sph_kernel<f4, 4><<<blocks, threads, 0, stream>>>(cart, out, N);
    } else {
        const int blocks = (N + threads - 1) / threads;
        sph_kernel<float, 1><<<blocks, threads, 0, stream>>>(cart, out, N);
    }
}